// Round 10
// baseline (9943.528 us; speedup 1.0000x reference)
//
#include <hip/hip_runtime.h>
#include <stdint.h>

// ---------------------------------------------------------------------------
// RNN rollout. Phase 1: MFMA teacher-forced recurrence (R18) + bulk psi
// (64-row blocks, R17). Phase 2: persistent AR kernel, 8 groups x 32
// members, member m -> XCD m%8 (weight slices L2-resident, R6/R8).
// Failed variants (do not retry): co-located groups (R9), in-grid psi
// fusion (R11), redundant full-L1 (R12), epoch-flag exchange (R13),
// MALL-atomic L5 reduction (R15), chunked per-layer psi GEMMs (R16).
// AR kernel = R14 structure VERBATIM (4770-4800us steady, best known).
// R18 change: k_rnn_tf (650us, scalar VALU dots, ~2.5us/step) replaced by
// k_rnn_tf2: 8 blocks x 16 batch rows x 128 thr, cell as MFMA (the SAME
// 8ct x 9kc pattern proven in the AR kernel, weights = WBC/CB verbatim).
// z kept in bf16 hi/lo split (zhi=f2bf(z), zlo=f2bf(z-zhi)) so the f32
// recurrence is reproduced to ~1e-4 and Zg snapshots stay exactly f2bf(z):
// 136 MFMA/wave/step vs 256-deep scalar dots. y[t] loads issue at loop top
// (used only by the last kc); Zg stored as swizzle-aware short8.
// WHH2/WIH2 packs now dead (launches dropped).
// Sizes fixed: B=128, T=256, HOR=512, OBS=32, LAT=256, HID=1024.
// ---------------------------------------------------------------------------

#define BATCH 128
#define TTF   256
#define HOR   512
#define OBS   32
#define LAT   256
#define HID   1024

#define GROUPS  8
#define MEMBERS 32
#define ARBLOCKS (GROUPS * MEMBERS)
#define ARTHREADS 128

typedef __attribute__((ext_vector_type(8))) short short8;
typedef __attribute__((ext_vector_type(4))) float floatx4;

// ---- workspace layout (bytes) ----
#define OFF_WB1   ((size_t)0)                          // 1024x256 bf16 ([col][k])
#define OFF_WB2   (OFF_WB1 + (size_t)HID*LAT*2)        // 1024x1024 bf16
#define OFF_WB3   (OFF_WB2 + (size_t)HID*HID*2)
#define OFF_WB4   (OFF_WB3 + (size_t)HID*HID*2)
#define OFF_WB5   (OFF_WB4 + (size_t)HID*HID*2)        // 32x1024 bf16
#define OFF_CB    (OFF_WB5 + (size_t)OBS*HID*2)        // 256 f32 (b_ih+b_hh)
#define OFF_WHH2  (OFF_CB + (size_t)LAT*4)             // (legacy gap)
#define OFF_WIH2  (OFF_WHH2 + (size_t)64*256*8)        // (legacy gap)
#define OFF_ZF    (OFF_WIH2 + (size_t)8*256*8)         // 128x256 f32
#define OFF_Z     (OFF_ZF + (size_t)BATCH*LAT*4)       // 32768x256 bf16
#define OFF_WBC   (OFF_Z + (size_t)BATCH*TTF*LAT*2)    // 256x288 bf16 cell matrix
#define OFF_HB    (OFF_WBC + (size_t)LAT*288*2)        // 8 x 2par x 4 x 16x1024 bf16
#define OFF_CTR   (OFF_HB + (size_t)GROUPS*8*16*HID*2) // 8 x 512B counters
#define OFF_END   (OFF_CTR + (size_t)GROUPS*512)

__device__ __forceinline__ uint16_t f2bf(float f) {
    uint32_t u = __float_as_uint(f);
    u += 0x7fffu + ((u >> 16) & 1u);   // RNE
    return (uint16_t)(u >> 16);
}
__device__ __forceinline__ float bf2f(uint16_t h) {
    return __uint_as_float((uint32_t)h << 16);
}

__device__ __forceinline__ float fast_tanh(float x) {
    float ax = fabsf(x);
    float e  = __expf(-2.f * ax);
    float r  = (1.f - e) / (1.f + e);
    return copysignf(r, x);
}

// XOR-granule swizzles (16B granule index ^ low bits of row). Producers store
// swizzled; the verbatim DMA lands swizzled in LDS; readers XOR back.
__device__ __forceinline__ int hswz(int row, int col) {   // h: stride 1024
    return row * 1024 + ((((col >> 3) ^ (row & 7)) << 3) | (col & 7));
}
__device__ __forceinline__ int zswz(int row, int col) {   // z: stride 256
    return row * 256 + ((((col >> 3) ^ (row & 7)) << 3) | (col & 7));
}

// 16B MALL-coherent store (sc0|sc1 write-through, proven R9/R10).
__device__ __forceinline__ void st16_mall(void* p, floatx4 v) {
    asm volatile("global_store_dwordx4 %0, %1, off sc0 sc1"
                 :: "v"(p), "v"(v) : "memory");
}

// async DMA global->LDS, 16 B/lane, aux=0x11 (CPol SC0|SC1): reads at MALL
// (coherent with the sc0|sc1 writers), does not allocate into L1/L2.
typedef const __attribute__((address_space(1))) void* gas_t;
typedef __attribute__((address_space(3))) void* las_t;
__device__ __forceinline__ void gl_lds16(const void* g, void* l) {
    __builtin_amdgcn_global_load_lds((gas_t)g, (las_t)l, 16, 0, 0x11);
}

// 32 KB h tile MALL -> LDS: per wave 16 issues x 1 KB, all in flight.
__device__ __forceinline__ void stage_h(const uint16_t* src, uint16_t* dst,
                                        int w, int L) {
    const char* gp = (const char*)src + w * 16384 + L * 16;
    char* lp = (char*)dst + w * 16384;
    #pragma unroll
    for (int i = 0; i < 16; i++)
        gl_lds16(gp + i * 1024, lp + i * 1024);
}

// ---------------------------------------------------------------------------
// K0 helpers
// ---------------------------------------------------------------------------
__global__ void k_cvt(const float* __restrict__ s, uint16_t* __restrict__ d, int n) {
    int i = blockIdx.x * 256 + threadIdx.x;
    if (i < n) d[i] = f2bf(s[i]);
}

__global__ void k_cb(const float* __restrict__ a, const float* __restrict__ b,
                     float* __restrict__ c) {
    int j = threadIdx.x;
    c[j] = a[j] + b[j];
}

__global__ void k_packc(const float* __restrict__ whh, const float* __restrict__ wih,
                        uint16_t* __restrict__ wbc) {
    int col = blockIdx.x;
    for (int k = threadIdx.x; k < 288; k += 256) {
        float v = (k < 256) ? whh[(size_t)col * 256 + k] : wih[(size_t)col * 32 + (k - 256)];
        wbc[(size_t)col * 288 + k] = f2bf(v);
    }
}

// ---------------------------------------------------------------------------
// K1 (R18): MFMA teacher-forced recurrence. 8 blocks x 16 rows, 128 thr.
// z kept as bf16 hi/lo split in LDS (reproduces the f32 chain to ~1e-4;
// Zg snapshot == f2bf(z) by construction). Cell = 8ct x (8 zhi + 8 zlo +
// 1 y) MFMA per wave, weights/bias = WBC/CB (AR-cell verbatim pattern).
// ---------------------------------------------------------------------------
__global__ __launch_bounds__(128) void k_rnn_tf2(
    const float* __restrict__ y, const uint16_t* __restrict__ wbc,
    const float* __restrict__ cb, uint16_t* __restrict__ Zg,
    float* __restrict__ zfinal)
{
    __shared__ alignas(16) uint16_t zhi[2][16 * 256];  // 16 KB, swizzled
    __shared__ alignas(16) uint16_t zlo[2][16 * 256];  // 16 KB, swizzled
    __shared__ alignas(16) uint16_t ys[16 * 32];       // 1 KB
    const int tid = threadIdx.x;
    const int w = tid >> 6, L = tid & 63, lm = L & 15, q = L >> 4, lm7 = lm & 7;
    const int b0 = blockIdx.x * 16;
    const int yr = tid >> 3, yc = (tid & 7) * 4;       // y loader: row, col4
    const floatx4 zero = {0.f, 0.f, 0.f, 0.f};

    float cbv[8];
    #pragma unroll
    for (int ct = 0; ct < 8; ct++) cbv[ct] = cb[w * 128 + ct * 16 + lm];

    for (int idx = tid; idx < 16 * 256; idx += 128) {
        zhi[0][idx] = 0; zlo[0][idx] = 0;
    }
    __syncthreads();

    #pragma unroll 1
    for (int t = 0; t < TTF; t++) {
        const int cur = t & 1, nxt = cur ^ 1;

        // 1. issue y[t] loads early (consumed only by the last kc)
        float4 yv = *(const float4*)(y + (size_t)(b0 + yr) * (TTF * OBS) + t * OBS + yc);

        // 2. Zg snapshot: z_t (= zhi) -> global, swizzle-aware short8.
        //    thread: row yr, granules g = (tid&7)*4..+3 (stride-1 in g for
        //    coalescing within each row's 512B segment)
        {
            const uint16_t* zsrc = zhi[cur] + yr * 256;
            uint16_t* zdst = Zg + ((size_t)(b0 + yr) * TTF + t) * LAT;
            #pragma unroll
            for (int k = 0; k < 4; k++) {
                int gidx = (tid & 7) * 4 + k;
                *(short8*)(zdst + gidx * 8) =
                    *(const short8*)(zsrc + ((gidx ^ (yr & 7)) << 3));
            }
        }

        // 3. cell z-part: 8ct x (8 zhi + 8 zlo) MFMA
        floatx4 acc[8];
        #pragma unroll
        for (int ct = 0; ct < 8; ct++) acc[ct] = zero;
        #pragma unroll 1
        for (int ct = 0; ct < 8; ct++) {
            const uint16_t* bbw = wbc + (size_t)(w * 128 + ct * 16 + lm) * 288 + q * 8;
            #pragma unroll
            for (int kc = 0; kc < 8; kc++) {
                int gz = (kc * 4 + q) ^ lm7;
                short8 a = *(const short8*)(zhi[cur] + lm * 256 + gz * 8);
                short8 b = *(const short8*)(bbw + kc * 32);
                acc[ct] = __builtin_amdgcn_mfma_f32_16x16x32_bf16(a, b, acc[ct], 0, 0, 0);
            }
            #pragma unroll
            for (int kc = 0; kc < 8; kc++) {
                int gz = (kc * 4 + q) ^ lm7;
                short8 a = *(const short8*)(zlo[cur] + lm * 256 + gz * 8);
                short8 b = *(const short8*)(bbw + kc * 32);
                acc[ct] = __builtin_amdgcn_mfma_f32_16x16x32_bf16(a, b, acc[ct], 0, 0, 0);
            }
        }

        // 4. land y into LDS (drain the early loads), barrier
        {
            uint32_t p0 = (uint32_t)f2bf(yv.x) | ((uint32_t)f2bf(yv.y) << 16);
            uint32_t p1 = (uint32_t)f2bf(yv.z) | ((uint32_t)f2bf(yv.w) << 16);
            uint2 pk; pk.x = p0; pk.y = p1;
            *(uint2*)(ys + yr * 32 + yc) = pk;
        }
        __syncthreads();

        // 5. y term (kc=8) + 6. tanh -> zhi/zlo parity-next
        #pragma unroll 1
        for (int ct = 0; ct < 8; ct++) {
            int ccol = w * 128 + ct * 16 + lm;
            const uint16_t* bbw = wbc + (size_t)ccol * 288 + q * 8;
            short8 ay = *(const short8*)(ys + lm * 32 + q * 8);
            short8 b = *(const short8*)(bbw + 8 * 32);
            floatx4 v = __builtin_amdgcn_mfma_f32_16x16x32_bf16(ay, b, acc[ct], 0, 0, 0);
            #pragma unroll
            for (int i = 0; i < 4; i++) {
                float zv = fast_tanh(v[i] + cbv[ct]);
                uint16_t h = f2bf(zv);
                int o = zswz(q * 4 + i, ccol);
                zhi[nxt][o] = h;
                zlo[nxt][o] = f2bf(zv - bf2f(h));
            }
        }
        __syncthreads();
    }

    // zfinal (f32): reconstruct hi+lo from the final parity (TTF & 1 == 0)
    for (int idx = tid; idx < 16 * 256; idx += 128) {
        int r = idx >> 8, c = idx & 255;
        int o = zswz(r, c);
        zfinal[(size_t)(b0 + r) * LAT + c] = bf2f(zhi[0][o]) + bf2f(zlo[0][o]);
    }
}

// ---------------------------------------------------------------------------
// K2 primary: bulk psi, 64 rows/block (512 blocks, 512 thr, 128KB LDS).
// ---------------------------------------------------------------------------
__global__ __launch_bounds__(512) void k_psi_bulk64(
    const uint16_t* __restrict__ Zg,
    const uint16_t* __restrict__ wb1, const uint16_t* __restrict__ wb2,
    const uint16_t* __restrict__ wb3, const uint16_t* __restrict__ wb4,
    const uint16_t* __restrict__ wb5,
    const float* __restrict__ b1, const float* __restrict__ b2,
    const float* __restrict__ b3, const float* __restrict__ b4,
    const float* __restrict__ b5, float* __restrict__ out)
{
    __shared__ uint16_t hbuf[64 * 1024];   // 128 KB, swizzled
    int tid = threadIdx.x;
    int w = tid >> 6, L = tid & 63, lm = L & 15, q = L >> 4;
    int rb = blockIdx.x * 64;
    int colbase = w * 128;
    floatx4 acc[4][8];
    const floatx4 zero = {0.f, 0.f, 0.f, 0.f};

    #pragma unroll
    for (int rf = 0; rf < 4; rf++)
        #pragma unroll
        for (int nt = 0; nt < 8; nt++) acc[rf][nt] = zero;
    for (int kc = 0; kc < 8; kc++) {
        short8 a[4];
        #pragma unroll
        for (int rf = 0; rf < 4; rf++)
            a[rf] = *(const short8*)(Zg + (size_t)(rb + rf * 16 + lm) * LAT + kc * 32 + q * 8);
        #pragma unroll
        for (int nt = 0; nt < 8; nt++) {
            int n = colbase + nt * 16 + lm;
            short8 bf = *(const short8*)(wb1 + (size_t)n * LAT + kc * 32 + q * 8);
            #pragma unroll
            for (int rf = 0; rf < 4; rf++)
                acc[rf][nt] = __builtin_amdgcn_mfma_f32_16x16x32_bf16(a[rf], bf, acc[rf][nt], 0, 0, 0);
        }
    }
    #pragma unroll
    for (int rf = 0; rf < 4; rf++)
        #pragma unroll
        for (int nt = 0; nt < 8; nt++) {
            int col = colbase + nt * 16 + lm;
            float bias = b1[col];
            #pragma unroll
            for (int i = 0; i < 4; i++) {
                int row = rf * 16 + q * 4 + i;
                hbuf[hswz(row, col)] = f2bf(fmaxf(acc[rf][nt][i] + bias, 0.f));
            }
        }
    __syncthreads();

    const uint16_t* wbs[3] = {wb2, wb3, wb4};
    const float*    bbs[3] = {b2, b3, b4};
    for (int ll = 0; ll < 3; ll++) {
        const uint16_t* wb = wbs[ll];
        const float* bb = bbs[ll];
        #pragma unroll
        for (int rf = 0; rf < 4; rf++)
            #pragma unroll
            for (int nt = 0; nt < 8; nt++) acc[rf][nt] = zero;
        for (int kc = 0; kc < 32; kc++) {
            int g = ((kc * 4 + q) ^ (lm & 7)) << 3;
            short8 a[4];
            #pragma unroll
            for (int rf = 0; rf < 4; rf++)
                a[rf] = *(const short8*)(hbuf + (rf * 16 + lm) * 1024 + g);
            #pragma unroll
            for (int nt = 0; nt < 8; nt++) {
                int n = colbase + nt * 16 + lm;
                short8 bf = *(const short8*)(wb + (size_t)n * HID + kc * 32 + q * 8);
                #pragma unroll
                for (int rf = 0; rf < 4; rf++)
                    acc[rf][nt] = __builtin_amdgcn_mfma_f32_16x16x32_bf16(a[rf], bf, acc[rf][nt], 0, 0, 0);
            }
        }
        __syncthreads();
        #pragma unroll
        for (int rf = 0; rf < 4; rf++)
            #pragma unroll
            for (int nt = 0; nt < 8; nt++) {
                int col = colbase + nt * 16 + lm;
                float bias = bb[col];
                #pragma unroll
                for (int i = 0; i < 4; i++) {
                    int row = rf * 16 + q * 4 + i;
                    hbuf[hswz(row, col)] = f2bf(fmaxf(acc[rf][nt][i] + bias, 0.f));
                }
            }
        __syncthreads();
    }

    // L5: all 8 waves -- wave w = row-frag (w>>1) x col-tile (w&1)
    {
        int rf5 = w >> 1;
        int nb = (w & 1) * 16;
        floatx4 a5 = zero;
        for (int kc = 0; kc < 32; kc++) {
            int g = ((kc * 4 + q) ^ (lm & 7)) << 3;
            short8 a = *(const short8*)(hbuf + (rf5 * 16 + lm) * 1024 + g);
            short8 bf = *(const short8*)(wb5 + (size_t)(nb + lm) * HID + kc * 32 + q * 8);
            a5 = __builtin_amdgcn_mfma_f32_16x16x32_bf16(a, bf, a5, 0, 0, 0);
        }
        int col = nb + lm;
        float bias = b5[col];
        #pragma unroll
        for (int i = 0; i < 4; i++) {
            int r = rb + rf5 * 16 + q * 4 + i;
            int bb_ = r >> 8, tt = r & 255;
            out[(size_t)bb_ * (HOR * OBS) + tt * OBS + col] = a5[i] + bias;
        }
    }
}

// ---------------------------------------------------------------------------
// K2 fallback: bulk psi, 32 rows/block (R10-proven). Launched only if the
// 64-row variant is rejected at launch (synchronous error check).
// ---------------------------------------------------------------------------
__global__ __launch_bounds__(512) void k_psi_bulk(
    const uint16_t* __restrict__ Zg,
    const uint16_t* __restrict__ wb1, const uint16_t* __restrict__ wb2,
    const uint16_t* __restrict__ wb3, const uint16_t* __restrict__ wb4,
    const uint16_t* __restrict__ wb5,
    const float* __restrict__ b1, const float* __restrict__ b2,
    const float* __restrict__ b3, const float* __restrict__ b4,
    const float* __restrict__ b5, float* __restrict__ out)
{
    __shared__ uint16_t hbuf[32 * 1024];   // 64 KB, swizzled
    int tid = threadIdx.x;
    int w = tid >> 6, L = tid & 63, lm = L & 15, q = L >> 4;
    int rb = blockIdx.x * 32;
    int colbase = w * 128;
    floatx4 acc[2][8];
    const floatx4 zero = {0.f, 0.f, 0.f, 0.f};

    #pragma unroll
    for (int mt = 0; mt < 2; mt++)
        #pragma unroll
        for (int nt = 0; nt < 8; nt++) acc[mt][nt] = zero;
    for (int kc = 0; kc < 8; kc++) {
        short8 a0 = *(const short8*)(Zg + (size_t)(rb + lm) * LAT + kc * 32 + q * 8);
        short8 a1 = *(const short8*)(Zg + (size_t)(rb + 16 + lm) * LAT + kc * 32 + q * 8);
        #pragma unroll
        for (int nt = 0; nt < 8; nt++) {
            int n = colbase + nt * 16 + lm;
            short8 bf = *(const short8*)(wb1 + (size_t)n * LAT + kc * 32 + q * 8);
            acc[0][nt] = __builtin_amdgcn_mfma_f32_16x16x32_bf16(a0, bf, acc[0][nt], 0, 0, 0);
            acc[1][nt] = __builtin_amdgcn_mfma_f32_16x16x32_bf16(a1, bf, acc[1][nt], 0, 0, 0);
        }
    }
    #pragma unroll
    for (int mt = 0; mt < 2; mt++)
        #pragma unroll
        for (int nt = 0; nt < 8; nt++) {
            int col = colbase + nt * 16 + lm;
            float bias = b1[col];
            #pragma unroll
            for (int i = 0; i < 4; i++) {
                int row = mt * 16 + q * 4 + i;
                hbuf[hswz(row, col)] = f2bf(fmaxf(acc[mt][nt][i] + bias, 0.f));
            }
        }
    __syncthreads();

    const uint16_t* wbs[3] = {wb2, wb3, wb4};
    const float*    bbs[3] = {b2, b3, b4};
    for (int ll = 0; ll < 3; ll++) {
        const uint16_t* wb = wbs[ll];
        const float* bb = bbs[ll];
        #pragma unroll
        for (int mt = 0; mt < 2; mt++)
            #pragma unroll
            for (int nt = 0; nt < 8; nt++) acc[mt][nt] = zero;
        for (int kc = 0; kc < 32; kc++) {
            int g = ((kc * 4 + q) ^ (lm & 7)) << 3;
            short8 a0 = *(const short8*)(hbuf + lm * 1024 + g);
            short8 a1 = *(const short8*)(hbuf + (16 + lm) * 1024 + g);
            #pragma unroll
            for (int nt = 0; nt < 8; nt++) {
                int n = colbase + nt * 16 + lm;
                short8 bf = *(const short8*)(wb + (size_t)n * HID + kc * 32 + q * 8);
                acc[0][nt] = __builtin_amdgcn_mfma_f32_16x16x32_bf16(a0, bf, acc[0][nt], 0, 0, 0);
                acc[1][nt] = __builtin_amdgcn_mfma_f32_16x16x32_bf16(a1, bf, acc[1][nt], 0, 0, 0);
            }
        }
        __syncthreads();
        #pragma unroll
        for (int mt = 0; mt < 2; mt++)
            #pragma unroll
            for (int nt = 0; nt < 8; nt++) {
                int col = colbase + nt * 16 + lm;
                float bias = bb[col];
                #pragma unroll
                for (int i = 0; i < 4; i++) {
                    int row = mt * 16 + q * 4 + i;
                    hbuf[hswz(row, col)] = f2bf(fmaxf(acc[mt][nt][i] + bias, 0.f));
                }
            }
        __syncthreads();
    }

    if (w < 4) {
        int mt = w >> 1;
        int nb = (w & 1) * 16;
        floatx4 a5 = zero;
        for (int kc = 0; kc < 32; kc++) {
            int g = ((kc * 4 + q) ^ (lm & 7)) << 3;
            short8 a = *(const short8*)(hbuf + (mt * 16 + lm) * 1024 + g);
            short8 bf = *(const short8*)(wb5 + (size_t)(nb + lm) * HID + kc * 32 + q * 8);
            a5 = __builtin_amdgcn_mfma_f32_16x16x32_bf16(a, bf, a5, 0, 0, 0);
        }
        int col = nb + lm;
        float bias = b5[col];
        #pragma unroll
        for (int i = 0; i < 4; i++) {
            int row = mt * 16 + q * 4 + i;
            int r = rb + row;
            int bb_ = r >> 8, tt = r & 255;
            out[(size_t)bb_ * (HOR * OBS) + tt * OBS + col] = a5[i] + bias;
        }
    }
}

// ---------------------------------------------------------------------------
// K3 v14 (unchanged): persistent AR. R10 hop structure, counter barrier split
// into ARRIVE (publish + drain + lane0 RMW) / overlap (cell z-part) / WAIT
// (tid0 spin + one __syncthreads). Tail: stage h4, L5, out, cell finish.
// ---------------------------------------------------------------------------
__global__ __launch_bounds__(ARTHREADS) void k_ar2(
    const float* __restrict__ zfinal,
    const uint16_t* __restrict__ wb1, const uint16_t* __restrict__ wb2,
    const uint16_t* __restrict__ wb3, const uint16_t* __restrict__ wb4,
    const uint16_t* __restrict__ wb5, const uint16_t* __restrict__ wbc,
    const float* __restrict__ b1g, const float* __restrict__ b2g,
    const float* __restrict__ b3g, const float* __restrict__ b4g,
    const float* __restrict__ b5g, const float* __restrict__ cb,
    uint16_t* __restrict__ hb_all, unsigned* __restrict__ ctr_all,
    float* __restrict__ out)
{
    __shared__ alignas(16) uint16_t hstg[16 * 1024];   // 32 KB staged h tile
    __shared__ alignas(16) uint16_t zst[2 * 16 * 256]; // 16 KB z parity buffers
    __shared__ alignas(16) uint16_t yscr[16 * 32];     // 1 KB
    __shared__ alignas(16) uint16_t hsl[16 * 32];      // 1 KB slice transpose

    const int tid = threadIdx.x;
    const int g = blockIdx.x >> 5, m = blockIdx.x & 31;   // member m -> XCD m%8
    const int w = tid >> 6, L = tid & 63, lm = L & 15, q = L >> 4, lm7 = lm & 7;
    const int colbase = m * 32;
    const int cl = w * 16 + lm;
    const int rb = g * 16;
    uint16_t* hb = hb_all + (size_t)g * (8 * 16 * HID);   // 2 parity x 4 slots
    unsigned* ctr = ctr_all + g * 128;
    const floatx4 zero = {0.f, 0.f, 0.f, 0.f};

    // loop-invariant bias loads, hoisted out of the t-loop
    const float b1v = b1g[colbase + cl];
    const float b2v = b2g[colbase + cl];
    const float b3v = b3g[colbase + cl];
    const float b4v = b4g[colbase + cl];
    const float b5v = b5g[cl];
    float cbv[8];
    #pragma unroll
    for (int ct = 0; ct < 8; ct++) cbv[ct] = cb[w * 128 + ct * 16 + lm];

    // initial z: local LDS only (every member keeps its own copy), swizzled
    for (int idx = tid; idx < 16 * 256; idx += ARTHREADS) {
        int r = idx >> 8, c = idx & 255;
        zst[zswz(r, c)] = f2bf(zfinal[(size_t)(rb + r) * LAT + c]);
    }
    __syncthreads();

    // ARRIVE: wave0 publishes slice, drains its stores, lane0 RMWs counter.
    #define HOP_ARRIVE(DST) do {                                             \
        __syncthreads();                                                     \
        if (tid < 64) {                                                      \
            int row_ = tid >> 2, gr_ = tid & 3;                              \
            floatx4 vv_ = *(const floatx4*)((const char*)hsl + tid * 16);    \
            int gsw_ = (m * 4 + gr_) ^ (row_ & 7);                           \
            st16_mall((char*)(DST) + row_ * 2048 + gsw_ * 16, vv_);          \
            asm volatile("s_waitcnt vmcnt(0)" ::: "memory");                 \
            if (tid == 0)                                                    \
                __hip_atomic_fetch_add(ctr, 1u, __ATOMIC_RELAXED,            \
                                       __HIP_MEMORY_SCOPE_AGENT);            \
        }                                                                    \
    } while (0)

    // WAIT: tid0 spins on the group counter, then one block barrier.
    #define HOP_WAIT(TGT) do {                                               \
        if (tid == 0) {                                                      \
            while (__hip_atomic_load(ctr, __ATOMIC_RELAXED,                  \
                                     __HIP_MEMORY_SCOPE_AGENT) < (TGT)) {}   \
        }                                                                    \
        __syncthreads();                                                     \
    } while (0)

    // cell z-part chunk: kc in [K0,K1), accumulated into cc[8]
    #define CCZ(K0, K1) do {                                                 \
        _Pragma("unroll")                                                    \
        for (int ct = 0; ct < 8; ct++) {                                     \
            const uint16_t* bb2_ = wbc + (size_t)(w * 128 + ct * 16 + lm) * 288 + q * 8; \
            _Pragma("unroll")                                                \
            for (int kc = (K0); kc < (K1); kc++) {                           \
                int gz_ = (kc * 4 + q) ^ lm7;                                \
                short8 a_ = *(const short8*)(zcur + lm * 256 + gz_ * 8);     \
                short8 b_ = *(const short8*)(bb2_ + kc * 32);                \
                cc[ct] = __builtin_amdgcn_mfma_f32_16x16x32_bf16(a_, b_, cc[ct], 0, 0, 0); \
            }                                                                \
        }                                                                    \
    } while (0)

    #define MID_COMPUTE(WB, BV) do {                                         \
        floatx4 acc_ = zero;                                                 \
        const uint16_t* bb_ = WB + (size_t)(colbase + cl) * HID + q * 8;     \
        _Pragma("unroll 8")                                                  \
        for (int kc = 0; kc < 32; kc++) {                                    \
            int gh = (kc * 4 + q) ^ lm7;                                     \
            short8 a_ = *(const short8*)(hstg + lm * 1024 + gh * 8);         \
            short8 b_ = *(const short8*)(bb_ + kc * 32);                     \
            acc_ = __builtin_amdgcn_mfma_f32_16x16x32_bf16(a_, b_, acc_, 0, 0, 0); \
        }                                                                    \
        _Pragma("unroll")                                                    \
        for (int i = 0; i < 4; i++)                                          \
            hsl[(q * 4 + i) * 32 + cl] = f2bf(fmaxf(acc_[i] + (BV), 0.f));   \
    } while (0)

    unsigned tgt = 0;
    #pragma unroll 1
    for (int t = 0; t < HOR - TTF; t++) {
        uint16_t* zcur = zst + (t & 1) * (16 * 256);
        uint16_t* znx  = zst + ((t + 1) & 1) * (16 * 256);
        uint16_t* hp = hb + (t & 1) * (4 * 16 * HID);     // step-parity tiles
        uint16_t* h1 = hp;
        uint16_t* h2 = hp + 16 * HID;
        uint16_t* h3 = hp + 2 * 16 * HID;
        uint16_t* h4 = hp + 3 * 16 * HID;

        floatx4 cc[8];
        #pragma unroll
        for (int ct = 0; ct < 8; ct++) cc[ct] = zero;

        // ---- L1 slice from LDS z (local) ----
        {
            floatx4 acc = zero;
            const uint16_t* bb = wb1 + (size_t)(colbase + cl) * LAT + q * 8;
            #pragma unroll
            for (int kc = 0; kc < 8; kc++) {
                int gz = (kc * 4 + q) ^ lm7;
                short8 a = *(const short8*)(zcur + lm * 256 + gz * 8);
                short8 b = *(const short8*)(bb + kc * 32);
                acc = __builtin_amdgcn_mfma_f32_16x16x32_bf16(a, b, acc, 0, 0, 0);
            }
            #pragma unroll
            for (int i = 0; i < 4; i++)
                hsl[(q * 4 + i) * 32 + cl] = f2bf(fmaxf(acc[i] + b1v, 0.f));
        }
        HOP_ARRIVE(h1); tgt += MEMBERS;
        CCZ(0, 2);
        HOP_WAIT(tgt);
        stage_h(h1, hstg, w, L);
        __syncthreads();

        MID_COMPUTE(wb2, b2v);
        HOP_ARRIVE(h2); tgt += MEMBERS;
        CCZ(2, 4);
        HOP_WAIT(tgt);
        stage_h(h2, hstg, w, L);
        __syncthreads();

        MID_COMPUTE(wb3, b3v);
        HOP_ARRIVE(h3); tgt += MEMBERS;
        CCZ(4, 6);
        HOP_WAIT(tgt);
        stage_h(h3, hstg, w, L);
        __syncthreads();

        MID_COMPUTE(wb4, b4v);
        HOP_ARRIVE(h4); tgt += MEMBERS;
        CCZ(6, 8);
        HOP_WAIT(tgt);
        stage_h(h4, hstg, w, L);
        __syncthreads();

        // ---- tail: L5 (redundant), out, cell finish (yh term) ----
        {
            floatx4 a5 = zero;
            const uint16_t* bb = wb5 + (size_t)cl * HID + q * 8;
            #pragma unroll 8
            for (int kc = 0; kc < 32; kc++) {
                int gh = (kc * 4 + q) ^ lm7;
                short8 a = *(const short8*)(hstg + lm * 1024 + gh * 8);
                short8 b = *(const short8*)(bb + kc * 32);
                a5 = __builtin_amdgcn_mfma_f32_16x16x32_bf16(a, b, a5, 0, 0, 0);
            }
            float vout[4];
            #pragma unroll
            for (int i = 0; i < 4; i++) {
                float v = a5[i] + b5v;
                vout[i] = v;
                yscr[(q * 4 + i) * 32 + cl] = f2bf(v);
            }
            if (m == 0) {
                #pragma unroll
                for (int i = 0; i < 4; i++)
                    out[(size_t)(rb + q * 4 + i) * (HOR * OBS) + (TTF + t) * OBS + cl] = vout[i];
            }
        }
        __syncthreads();
        // cell finish: add the yh term (kc=8) to cc[], tanh, write z'
        {
            short8 ay = *(const short8*)(yscr + lm * 32 + q * 8);
            #pragma unroll
            for (int ct = 0; ct < 8; ct++) {
                int ccol = w * 128 + ct * 16 + lm;
                const uint16_t* bb2 = wbc + (size_t)ccol * 288 + q * 8;
                short8 b = *(const short8*)(bb2 + 8 * 32);
                floatx4 v = __builtin_amdgcn_mfma_f32_16x16x32_bf16(ay, b, cc[ct], 0, 0, 0);
                #pragma unroll
                for (int i = 0; i < 4; i++)
                    znx[zswz(q * 4 + i, ccol)] = f2bf(fast_tanh(v[i] + cbv[ct]));
            }
        }
        __syncthreads();
    }
    #undef MID_COMPUTE
    #undef CCZ
    #undef HOP_WAIT
    #undef HOP_ARRIVE
}

// ---------------------------------------------------------------------------
extern "C" void kernel_launch(void* const* d_in, const int* in_sizes, int n_in,
                              void* d_out, int out_size, void* d_ws, size_t ws_size,
                              hipStream_t stream) {
    (void)in_sizes; (void)n_in; (void)out_size; (void)ws_size;
    const float* y    = (const float*)d_in[0];
    const float* W_ih = (const float*)d_in[2];
    const float* W_hh = (const float*)d_in[3];
    const float* b_ih = (const float*)d_in[4];
    const float* b_hh = (const float*)d_in[5];
    const float* W1   = (const float*)d_in[6];
    const float* b1   = (const float*)d_in[7];
    const float* W2   = (const float*)d_in[8];
    const float* b2   = (const float*)d_in[9];
    const float* W3   = (const float*)d_in[10];
    const float* b3   = (const float*)d_in[11];
    const float* W4   = (const float*)d_in[12];
    const float* b4   = (const float*)d_in[13];
    const float* W5   = (const float*)d_in[14];
    const float* b5   = (const float*)d_in[15];
    float* out = (float*)d_out;
    char* ws = (char*)d_ws;

    uint16_t* WB1  = (uint16_t*)(ws + OFF_WB1);
    uint16_t* WB2  = (uint16_t*)(ws + OFF_WB2);
    uint16_t* WB3  = (uint16_t*)(ws + OFF_WB3);
    uint16_t* WB4  = (uint16_t*)(ws + OFF_WB4);
    uint16_t* WB5  = (uint16_t*)(ws + OFF_WB5);
    float*    CB   = (float*)(ws + OFF_CB);
    float*    ZF   = (float*)(ws + OFF_ZF);
    uint16_t* Zbuf = (uint16_t*)(ws + OFF_Z);
    uint16_t* WBC  = (uint16_t*)(ws + OFF_WBC);
    uint16_t* HB   = (uint16_t*)(ws + OFF_HB);
    unsigned* CTR  = (unsigned*)(ws + OFF_CTR);

    k_cvt<<<(HID*LAT + 255) / 256, 256, 0, stream>>>(W1, WB1, HID * LAT);
    k_cvt<<<(HID*HID + 255) / 256, 256, 0, stream>>>(W2, WB2, HID * HID);
    k_cvt<<<(HID*HID + 255) / 256, 256, 0, stream>>>(W3, WB3, HID * HID);
    k_cvt<<<(HID*HID + 255) / 256, 256, 0, stream>>>(W4, WB4, HID * HID);
    k_cvt<<<(OBS*HID + 255) / 256, 256, 0, stream>>>(W5, WB5, OBS * HID);
    k_cb<<<1, 256, 0, stream>>>(b_ih, b_hh, CB);
    k_packc<<<256, 256, 0, stream>>>(W_hh, W_ih, WBC);
    hipMemsetAsync(CTR, 0, GROUPS * 512, stream);

    // R18: MFMA teacher-forced recurrence (8 blocks x 16 rows)
    k_rnn_tf2<<<GROUPS, 128, 0, stream>>>(y, WBC, CB, Zbuf, ZF);

    // psi: 64-row blocks (halved weight traffic); fall back to the proven
    // 32-row version on any synchronous launch error (e.g. LDS rejection).
    k_psi_bulk64<<<(BATCH * TTF) / 64, 512, 0, stream>>>(
        Zbuf, WB1, WB2, WB3, WB4, WB5, b1, b2, b3, b4, b5, out);
    hipError_t pe = hipGetLastError();
    if (pe != hipSuccess) {
        k_psi_bulk<<<(BATCH * TTF) / 32, 512, 0, stream>>>(
            Zbuf, WB1, WB2, WB3, WB4, WB5, b1, b2, b3, b4, b5, out);
    }

    // Cooperative launch preferred (guaranteed co-residency); on ANY error
    // fall back to a plain launch — 256 blocks at 1+/CU are co-resident.
    void* args[] = {
        (void*)&ZF, (void*)&WB1, (void*)&WB2, (void*)&WB3, (void*)&WB4,
        (void*)&WB5, (void*)&WBC, (void*)&b1, (void*)&b2, (void*)&b3,
        (void*)&b4, (void*)&b5, (void*)&CB, (void*)&HB, (void*)&CTR,
        (void*)&out
    };
    hipError_t ce = hipLaunchCooperativeKernel((const void*)k_ar2,
                                               dim3(ARBLOCKS), dim3(ARTHREADS),
                                               args, 0, stream);
    if (ce != hipSuccess) {
        (void)hipGetLastError();   // clear sticky error
        k_ar2<<<dim3(ARBLOCKS), dim3(ARTHREADS), 0, stream>>>(
            ZF, WB1, WB2, WB3, WB4, WB5, WBC, b1, b2, b3, b4, b5, CB,
            HB, CTR, out);
    }
}

// Round 11
// 6142.126 us; speedup vs baseline: 1.6189x; 1.6189x over previous
//
#include <hip/hip_runtime.h>
#include <stdint.h>

// ---------------------------------------------------------------------------
// RNN rollout. Phase 1: teacher-forced recurrence (scalar, 4-way ILP, R19) +
// bulk psi (64-row blocks, R17). Phase 2: persistent AR kernel, 8 groups x
// 32 members, member m -> XCD m%8 (weight slices L2-resident, R6/R8).
// Failed variants (do not retry): co-located groups (R9), in-grid psi
// fusion (R11), redundant full-L1 (R12), epoch-flag exchange (R13),
// MALL-atomic L5 reduction (R15), chunked per-layer psi GEMMs (R16),
// MFMA teacher-forced recurrence (R18: 16-row tiles => 8 blocks = 16 waves
// on 256 CUs, zero latency hiding, 650us -> 4300us).
// AR kernel = R14 structure VERBATIM (4770-4800us steady, best known).
// R19 change (inside scalar k_rnn_tf only): the 288-FMA dot was ONE
// dependent chain (~288 x 4cyc + load latency on the critical path).
// Now 4 independent partial accumulators (4x ILP) + y[t+1] register
// prefetch during compute + hoisted cb[j]. Summation-order delta ~1e-7
// through contractive tanh -- output unchanged at bf16 granularity.
// Sizes fixed: B=128, T=256, HOR=512, OBS=32, LAT=256, HID=1024.
// ---------------------------------------------------------------------------

#define BATCH 128
#define TTF   256
#define HOR   512
#define OBS   32
#define LAT   256
#define HID   1024

#define GROUPS  8
#define MEMBERS 32
#define ARBLOCKS (GROUPS * MEMBERS)
#define ARTHREADS 128

typedef __attribute__((ext_vector_type(8))) short short8;
typedef __attribute__((ext_vector_type(4))) float floatx4;

// ---- workspace layout (bytes) ----
#define OFF_WB1   ((size_t)0)                          // 1024x256 bf16 ([col][k])
#define OFF_WB2   (OFF_WB1 + (size_t)HID*LAT*2)        // 1024x1024 bf16
#define OFF_WB3   (OFF_WB2 + (size_t)HID*HID*2)
#define OFF_WB4   (OFF_WB3 + (size_t)HID*HID*2)
#define OFF_WB5   (OFF_WB4 + (size_t)HID*HID*2)        // 32x1024 bf16
#define OFF_CB    (OFF_WB5 + (size_t)OBS*HID*2)        // 256 f32 (b_ih+b_hh)
#define OFF_WHH2  (OFF_CB + (size_t)LAT*4)             // 64x256 uint2 packed W_hh^T
#define OFF_WIH2  (OFF_WHH2 + (size_t)64*256*8)        // 8x256 uint2 packed W_ih^T
#define OFF_ZF    (OFF_WIH2 + (size_t)8*256*8)         // 128x256 f32
#define OFF_Z     (OFF_ZF + (size_t)BATCH*LAT*4)       // 32768x256 bf16
#define OFF_WBC   (OFF_Z + (size_t)BATCH*TTF*LAT*2)    // 256x288 bf16 cell matrix
#define OFF_HB    (OFF_WBC + (size_t)LAT*288*2)        // 8 x 2par x 4 x 16x1024 bf16
#define OFF_CTR   (OFF_HB + (size_t)GROUPS*8*16*HID*2) // 8 x 512B counters
#define OFF_END   (OFF_CTR + (size_t)GROUPS*512)

__device__ __forceinline__ uint16_t f2bf(float f) {
    uint32_t u = __float_as_uint(f);
    u += 0x7fffu + ((u >> 16) & 1u);   // RNE
    return (uint16_t)(u >> 16);
}
__device__ __forceinline__ float bflo(uint32_t u) { return __uint_as_float(u << 16); }
__device__ __forceinline__ float bfhi(uint32_t u) { return __uint_as_float(u & 0xffff0000u); }

__device__ __forceinline__ float fast_tanh(float x) {
    float ax = fabsf(x);
    float e  = __expf(-2.f * ax);
    float r  = (1.f - e) / (1.f + e);
    return copysignf(r, x);
}

// XOR-granule swizzles (16B granule index ^ low bits of row). Producers store
// swizzled; the verbatim DMA lands swizzled in LDS; readers XOR back.
__device__ __forceinline__ int hswz(int row, int col) {   // h: stride 1024
    return row * 1024 + ((((col >> 3) ^ (row & 7)) << 3) | (col & 7));
}
__device__ __forceinline__ int zswz(int row, int col) {   // z: stride 256
    return row * 256 + ((((col >> 3) ^ (row & 7)) << 3) | (col & 7));
}

// 16B MALL-coherent store (sc0|sc1 write-through, proven R9/R10).
__device__ __forceinline__ void st16_mall(void* p, floatx4 v) {
    asm volatile("global_store_dwordx4 %0, %1, off sc0 sc1"
                 :: "v"(p), "v"(v) : "memory");
}

// async DMA global->LDS, 16 B/lane, aux=0x11 (CPol SC0|SC1): reads at MALL
// (coherent with the sc0|sc1 writers), does not allocate into L1/L2.
typedef const __attribute__((address_space(1))) void* gas_t;
typedef __attribute__((address_space(3))) void* las_t;
__device__ __forceinline__ void gl_lds16(const void* g, void* l) {
    __builtin_amdgcn_global_load_lds((gas_t)g, (las_t)l, 16, 0, 0x11);
}

// 32 KB h tile MALL -> LDS: per wave 16 issues x 1 KB, all in flight.
__device__ __forceinline__ void stage_h(const uint16_t* src, uint16_t* dst,
                                        int w, int L) {
    const char* gp = (const char*)src + w * 16384 + L * 16;
    char* lp = (char*)dst + w * 16384;
    #pragma unroll
    for (int i = 0; i < 16; i++)
        gl_lds16(gp + i * 1024, lp + i * 1024);
}

// ---------------------------------------------------------------------------
// K0 helpers
// ---------------------------------------------------------------------------
__global__ void k_cvt(const float* __restrict__ s, uint16_t* __restrict__ d, int n) {
    int i = blockIdx.x * 256 + threadIdx.x;
    if (i < n) d[i] = f2bf(s[i]);
}

__global__ void k_cb(const float* __restrict__ a, const float* __restrict__ b,
                     float* __restrict__ c) {
    int j = threadIdx.x;
    c[j] = a[j] + b[j];
}

__global__ void k_pack(const float* __restrict__ w, uint2* __restrict__ dst, int klen) {
    int k4 = blockIdx.x, j = threadIdx.x;
    int k = k4 * 4;
    uint32_t a = f2bf(w[(size_t)j * klen + k + 0]);
    uint32_t b = f2bf(w[(size_t)j * klen + k + 1]);
    uint32_t c = f2bf(w[(size_t)j * klen + k + 2]);
    uint32_t d = f2bf(w[(size_t)j * klen + k + 3]);
    uint2 r; r.x = a | (b << 16); r.y = c | (d << 16);
    dst[k4 * 256 + j] = r;
}

__global__ void k_packc(const float* __restrict__ whh, const float* __restrict__ wih,
                        uint16_t* __restrict__ wbc) {
    int col = blockIdx.x;
    for (int k = threadIdx.x; k < 288; k += 256) {
        float v = (k < 256) ? whh[(size_t)col * 256 + k] : wih[(size_t)col * 32 + (k - 256)];
        wbc[(size_t)col * 288 + k] = f2bf(v);
    }
}

// ---------------------------------------------------------------------------
// K1 (R19): teacher-forced recurrence, scalar with 4-way ILP + y prefetch.
// 128 blocks x 256 threads.
// ---------------------------------------------------------------------------
__global__ __launch_bounds__(256) void k_rnn_tf(
    const float* __restrict__ y, const uint2* __restrict__ whh2,
    const uint2* __restrict__ wih2, const float* __restrict__ cb,
    uint16_t* __restrict__ Zg, float* __restrict__ zfinal)
{
    __shared__ alignas(16) float zl[LAT];
    __shared__ alignas(16) float ys[OBS];
    int j = threadIdx.x, b = blockIdx.x;
    zl[j] = 0.f;
    const float cbj = cb[j];
    float ynext = (j < OBS) ? y[(size_t)b * (TTF * OBS) + j] : 0.f;
    __syncthreads();
    const float4* z4 = (const float4*)zl;
    const float4* y4 = (const float4*)ys;
    for (int t = 0; t < TTF; t++) {
        if (j < OBS) ys[j] = ynext;
        Zg[((size_t)b * TTF + t) * LAT + j] = f2bf(zl[j]);
        __syncthreads();
        // prefetch y[t+1] during the compute (off the critical path)
        if (t + 1 < TTF && j < OBS)
            ynext = y[(size_t)b * (TTF * OBS) + (t + 1) * OBS + j];
        // 4 independent accumulator chains (breaks the 288-FMA dependency)
        float a0 = cbj, a1 = 0.f, a2 = 0.f, a3 = 0.f;
        #pragma unroll 4
        for (int k4 = 0; k4 < 64; k4 += 4) {
            uint2 w0 = whh2[(k4 + 0) * 256 + j]; float4 z0 = z4[k4 + 0];
            uint2 w1 = whh2[(k4 + 1) * 256 + j]; float4 z1 = z4[k4 + 1];
            uint2 w2 = whh2[(k4 + 2) * 256 + j]; float4 z2 = z4[k4 + 2];
            uint2 w3 = whh2[(k4 + 3) * 256 + j]; float4 z3 = z4[k4 + 3];
            a0 += bflo(w0.x) * z0.x + bfhi(w0.x) * z0.y
                + bflo(w0.y) * z0.z + bfhi(w0.y) * z0.w;
            a1 += bflo(w1.x) * z1.x + bfhi(w1.x) * z1.y
                + bflo(w1.y) * z1.z + bfhi(w1.y) * z1.w;
            a2 += bflo(w2.x) * z2.x + bfhi(w2.x) * z2.y
                + bflo(w2.y) * z2.z + bfhi(w2.y) * z2.w;
            a3 += bflo(w3.x) * z3.x + bfhi(w3.x) * z3.y
                + bflo(w3.y) * z3.z + bfhi(w3.y) * z3.w;
        }
        #pragma unroll
        for (int k4 = 0; k4 < 8; k4 += 4) {
            uint2 w0 = wih2[(k4 + 0) * 256 + j]; float4 q0 = y4[k4 + 0];
            uint2 w1 = wih2[(k4 + 1) * 256 + j]; float4 q1 = y4[k4 + 1];
            uint2 w2 = wih2[(k4 + 2) * 256 + j]; float4 q2 = y4[k4 + 2];
            uint2 w3 = wih2[(k4 + 3) * 256 + j]; float4 q3 = y4[k4 + 3];
            a0 += bflo(w0.x) * q0.x + bfhi(w0.x) * q0.y
                + bflo(w0.y) * q0.z + bfhi(w0.y) * q0.w;
            a1 += bflo(w1.x) * q1.x + bfhi(w1.x) * q1.y
                + bflo(w1.y) * q1.z + bfhi(w1.y) * q1.w;
            a2 += bflo(w2.x) * q2.x + bfhi(w2.x) * q2.y
                + bflo(w2.y) * q2.z + bfhi(w2.y) * q2.w;
            a3 += bflo(w3.x) * q3.x + bfhi(w3.x) * q3.y
                + bflo(w3.y) * q3.z + bfhi(w3.y) * q3.w;
        }
        float acc = (a0 + a1) + (a2 + a3);
        __syncthreads();
        zl[j] = fast_tanh(acc);
    }
    __syncthreads();
    zfinal[(size_t)b * LAT + j] = zl[j];
}

// ---------------------------------------------------------------------------
// K2 primary: bulk psi, 64 rows/block (512 blocks, 512 thr, 128KB LDS).
// ---------------------------------------------------------------------------
__global__ __launch_bounds__(512) void k_psi_bulk64(
    const uint16_t* __restrict__ Zg,
    const uint16_t* __restrict__ wb1, const uint16_t* __restrict__ wb2,
    const uint16_t* __restrict__ wb3, const uint16_t* __restrict__ wb4,
    const uint16_t* __restrict__ wb5,
    const float* __restrict__ b1, const float* __restrict__ b2,
    const float* __restrict__ b3, const float* __restrict__ b4,
    const float* __restrict__ b5, float* __restrict__ out)
{
    __shared__ uint16_t hbuf[64 * 1024];   // 128 KB, swizzled
    int tid = threadIdx.x;
    int w = tid >> 6, L = tid & 63, lm = L & 15, q = L >> 4;
    int rb = blockIdx.x * 64;
    int colbase = w * 128;
    floatx4 acc[4][8];
    const floatx4 zero = {0.f, 0.f, 0.f, 0.f};

    #pragma unroll
    for (int rf = 0; rf < 4; rf++)
        #pragma unroll
        for (int nt = 0; nt < 8; nt++) acc[rf][nt] = zero;
    for (int kc = 0; kc < 8; kc++) {
        short8 a[4];
        #pragma unroll
        for (int rf = 0; rf < 4; rf++)
            a[rf] = *(const short8*)(Zg + (size_t)(rb + rf * 16 + lm) * LAT + kc * 32 + q * 8);
        #pragma unroll
        for (int nt = 0; nt < 8; nt++) {
            int n = colbase + nt * 16 + lm;
            short8 bf = *(const short8*)(wb1 + (size_t)n * LAT + kc * 32 + q * 8);
            #pragma unroll
            for (int rf = 0; rf < 4; rf++)
                acc[rf][nt] = __builtin_amdgcn_mfma_f32_16x16x32_bf16(a[rf], bf, acc[rf][nt], 0, 0, 0);
        }
    }
    #pragma unroll
    for (int rf = 0; rf < 4; rf++)
        #pragma unroll
        for (int nt = 0; nt < 8; nt++) {
            int col = colbase + nt * 16 + lm;
            float bias = b1[col];
            #pragma unroll
            for (int i = 0; i < 4; i++) {
                int row = rf * 16 + q * 4 + i;
                hbuf[hswz(row, col)] = f2bf(fmaxf(acc[rf][nt][i] + bias, 0.f));
            }
        }
    __syncthreads();

    const uint16_t* wbs[3] = {wb2, wb3, wb4};
    const float*    bbs[3] = {b2, b3, b4};
    for (int ll = 0; ll < 3; ll++) {
        const uint16_t* wb = wbs[ll];
        const float* bb = bbs[ll];
        #pragma unroll
        for (int rf = 0; rf < 4; rf++)
            #pragma unroll
            for (int nt = 0; nt < 8; nt++) acc[rf][nt] = zero;
        for (int kc = 0; kc < 32; kc++) {
            int g = ((kc * 4 + q) ^ (lm & 7)) << 3;
            short8 a[4];
            #pragma unroll
            for (int rf = 0; rf < 4; rf++)
                a[rf] = *(const short8*)(hbuf + (rf * 16 + lm) * 1024 + g);
            #pragma unroll
            for (int nt = 0; nt < 8; nt++) {
                int n = colbase + nt * 16 + lm;
                short8 bf = *(const short8*)(wb + (size_t)n * HID + kc * 32 + q * 8);
                #pragma unroll
                for (int rf = 0; rf < 4; rf++)
                    acc[rf][nt] = __builtin_amdgcn_mfma_f32_16x16x32_bf16(a[rf], bf, acc[rf][nt], 0, 0, 0);
            }
        }
        __syncthreads();
        #pragma unroll
        for (int rf = 0; rf < 4; rf++)
            #pragma unroll
            for (int nt = 0; nt < 8; nt++) {
                int col = colbase + nt * 16 + lm;
                float bias = bb[col];
                #pragma unroll
                for (int i = 0; i < 4; i++) {
                    int row = rf * 16 + q * 4 + i;
                    hbuf[hswz(row, col)] = f2bf(fmaxf(acc[rf][nt][i] + bias, 0.f));
                }
            }
        __syncthreads();
    }

    // L5: all 8 waves -- wave w = row-frag (w>>1) x col-tile (w&1)
    {
        int rf5 = w >> 1;
        int nb = (w & 1) * 16;
        floatx4 a5 = zero;
        for (int kc = 0; kc < 32; kc++) {
            int g = ((kc * 4 + q) ^ (lm & 7)) << 3;
            short8 a = *(const short8*)(hbuf + (rf5 * 16 + lm) * 1024 + g);
            short8 bf = *(const short8*)(wb5 + (size_t)(nb + lm) * HID + kc * 32 + q * 8);
            a5 = __builtin_amdgcn_mfma_f32_16x16x32_bf16(a, bf, a5, 0, 0, 0);
        }
        int col = nb + lm;
        float bias = b5[col];
        #pragma unroll
        for (int i = 0; i < 4; i++) {
            int r = rb + rf5 * 16 + q * 4 + i;
            int bb_ = r >> 8, tt = r & 255;
            out[(size_t)bb_ * (HOR * OBS) + tt * OBS + col] = a5[i] + bias;
        }
    }
}

// ---------------------------------------------------------------------------
// K2 fallback: bulk psi, 32 rows/block (R10-proven). Launched only if the
// 64-row variant is rejected at launch (synchronous error check).
// ---------------------------------------------------------------------------
__global__ __launch_bounds__(512) void k_psi_bulk(
    const uint16_t* __restrict__ Zg,
    const uint16_t* __restrict__ wb1, const uint16_t* __restrict__ wb2,
    const uint16_t* __restrict__ wb3, const uint16_t* __restrict__ wb4,
    const uint16_t* __restrict__ wb5,
    const float* __restrict__ b1, const float* __restrict__ b2,
    const float* __restrict__ b3, const float* __restrict__ b4,
    const float* __restrict__ b5, float* __restrict__ out)
{
    __shared__ uint16_t hbuf[32 * 1024];   // 64 KB, swizzled
    int tid = threadIdx.x;
    int w = tid >> 6, L = tid & 63, lm = L & 15, q = L >> 4;
    int rb = blockIdx.x * 32;
    int colbase = w * 128;
    floatx4 acc[2][8];
    const floatx4 zero = {0.f, 0.f, 0.f, 0.f};

    #pragma unroll
    for (int mt = 0; mt < 2; mt++)
        #pragma unroll
        for (int nt = 0; nt < 8; nt++) acc[mt][nt] = zero;
    for (int kc = 0; kc < 8; kc++) {
        short8 a0 = *(const short8*)(Zg + (size_t)(rb + lm) * LAT + kc * 32 + q * 8);
        short8 a1 = *(const short8*)(Zg + (size_t)(rb + 16 + lm) * LAT + kc * 32 + q * 8);
        #pragma unroll
        for (int nt = 0; nt < 8; nt++) {
            int n = colbase + nt * 16 + lm;
            short8 bf = *(const short8*)(wb1 + (size_t)n * LAT + kc * 32 + q * 8);
            acc[0][nt] = __builtin_amdgcn_mfma_f32_16x16x32_bf16(a0, bf, acc[0][nt], 0, 0, 0);
            acc[1][nt] = __builtin_amdgcn_mfma_f32_16x16x32_bf16(a1, bf, acc[1][nt], 0, 0, 0);
        }
    }
    #pragma unroll
    for (int mt = 0; mt < 2; mt++)
        #pragma unroll
        for (int nt = 0; nt < 8; nt++) {
            int col = colbase + nt * 16 + lm;
            float bias = b1[col];
            #pragma unroll
            for (int i = 0; i < 4; i++) {
                int row = mt * 16 + q * 4 + i;
                hbuf[hswz(row, col)] = f2bf(fmaxf(acc[mt][nt][i] + bias, 0.f));
            }
        }
    __syncthreads();

    const uint16_t* wbs[3] = {wb2, wb3, wb4};
    const float*    bbs[3] = {b2, b3, b4};
    for (int ll = 0; ll < 3; ll++) {
        const uint16_t* wb = wbs[ll];
        const float* bb = bbs[ll];
        #pragma unroll
        for (int mt = 0; mt < 2; mt++)
            #pragma unroll
            for (int nt = 0; nt < 8; nt++) acc[mt][nt] = zero;
        for (int kc = 0; kc < 32; kc++) {
            int g = ((kc * 4 + q) ^ (lm & 7)) << 3;
            short8 a0 = *(const short8*)(hbuf + lm * 1024 + g);
            short8 a1 = *(const short8*)(hbuf + (16 + lm) * 1024 + g);
            #pragma unroll
            for (int nt = 0; nt < 8; nt++) {
                int n = colbase + nt * 16 + lm;
                short8 bf = *(const short8*)(wb + (size_t)n * HID + kc * 32 + q * 8);
                acc[0][nt] = __builtin_amdgcn_mfma_f32_16x16x32_bf16(a0, bf, acc[0][nt], 0, 0, 0);
                acc[1][nt] = __builtin_amdgcn_mfma_f32_16x16x32_bf16(a1, bf, acc[1][nt], 0, 0, 0);
            }
        }
        __syncthreads();
        #pragma unroll
        for (int mt = 0; mt < 2; mt++)
            #pragma unroll
            for (int nt = 0; nt < 8; nt++) {
                int col = colbase + nt * 16 + lm;
                float bias = bb[col];
                #pragma unroll
                for (int i = 0; i < 4; i++) {
                    int row = mt * 16 + q * 4 + i;
                    hbuf[hswz(row, col)] = f2bf(fmaxf(acc[mt][nt][i] + bias, 0.f));
                }
            }
        __syncthreads();
    }

    if (w < 4) {
        int mt = w >> 1;
        int nb = (w & 1) * 16;
        floatx4 a5 = zero;
        for (int kc = 0; kc < 32; kc++) {
            int g = ((kc * 4 + q) ^ (lm & 7)) << 3;
            short8 a = *(const short8*)(hbuf + (mt * 16 + lm) * 1024 + g);
            short8 bf = *(const short8*)(wb5 + (size_t)(nb + lm) * HID + kc * 32 + q * 8);
            a5 = __builtin_amdgcn_mfma_f32_16x16x32_bf16(a, bf, a5, 0, 0, 0);
        }
        int col = nb + lm;
        float bias = b5[col];
        #pragma unroll
        for (int i = 0; i < 4; i++) {
            int row = mt * 16 + q * 4 + i;
            int r = rb + row;
            int bb_ = r >> 8, tt = r & 255;
            out[(size_t)bb_ * (HOR * OBS) + tt * OBS + col] = a5[i] + bias;
        }
    }
}

// ---------------------------------------------------------------------------
// K3 v14 (unchanged): persistent AR. R10 hop structure, counter barrier split
// into ARRIVE (publish + drain + lane0 RMW) / overlap (cell z-part) / WAIT
// (tid0 spin + one __syncthreads). Tail: stage h4, L5, out, cell finish.
// ---------------------------------------------------------------------------
__global__ __launch_bounds__(ARTHREADS) void k_ar2(
    const float* __restrict__ zfinal,
    const uint16_t* __restrict__ wb1, const uint16_t* __restrict__ wb2,
    const uint16_t* __restrict__ wb3, const uint16_t* __restrict__ wb4,
    const uint16_t* __restrict__ wb5, const uint16_t* __restrict__ wbc,
    const float* __restrict__ b1g, const float* __restrict__ b2g,
    const float* __restrict__ b3g, const float* __restrict__ b4g,
    const float* __restrict__ b5g, const float* __restrict__ cb,
    uint16_t* __restrict__ hb_all, unsigned* __restrict__ ctr_all,
    float* __restrict__ out)
{
    __shared__ alignas(16) uint16_t hstg[16 * 1024];   // 32 KB staged h tile
    __shared__ alignas(16) uint16_t zst[2 * 16 * 256]; // 16 KB z parity buffers
    __shared__ alignas(16) uint16_t yscr[16 * 32];     // 1 KB
    __shared__ alignas(16) uint16_t hsl[16 * 32];      // 1 KB slice transpose

    const int tid = threadIdx.x;
    const int g = blockIdx.x >> 5, m = blockIdx.x & 31;   // member m -> XCD m%8
    const int w = tid >> 6, L = tid & 63, lm = L & 15, q = L >> 4, lm7 = lm & 7;
    const int colbase = m * 32;
    const int cl = w * 16 + lm;
    const int rb = g * 16;
    uint16_t* hb = hb_all + (size_t)g * (8 * 16 * HID);   // 2 parity x 4 slots
    unsigned* ctr = ctr_all + g * 128;
    const floatx4 zero = {0.f, 0.f, 0.f, 0.f};

    // loop-invariant bias loads, hoisted out of the t-loop
    const float b1v = b1g[colbase + cl];
    const float b2v = b2g[colbase + cl];
    const float b3v = b3g[colbase + cl];
    const float b4v = b4g[colbase + cl];
    const float b5v = b5g[cl];
    float cbv[8];
    #pragma unroll
    for (int ct = 0; ct < 8; ct++) cbv[ct] = cb[w * 128 + ct * 16 + lm];

    // initial z: local LDS only (every member keeps its own copy), swizzled
    for (int idx = tid; idx < 16 * 256; idx += ARTHREADS) {
        int r = idx >> 8, c = idx & 255;
        zst[zswz(r, c)] = f2bf(zfinal[(size_t)(rb + r) * LAT + c]);
    }
    __syncthreads();

    // ARRIVE: wave0 publishes slice, drains its stores, lane0 RMWs counter.
    #define HOP_ARRIVE(DST) do {                                             \
        __syncthreads();                                                     \
        if (tid < 64) {                                                      \
            int row_ = tid >> 2, gr_ = tid & 3;                              \
            floatx4 vv_ = *(const floatx4*)((const char*)hsl + tid * 16);    \
            int gsw_ = (m * 4 + gr_) ^ (row_ & 7);                           \
            st16_mall((char*)(DST) + row_ * 2048 + gsw_ * 16, vv_);          \
            asm volatile("s_waitcnt vmcnt(0)" ::: "memory");                 \
            if (tid == 0)                                                    \
                __hip_atomic_fetch_add(ctr, 1u, __ATOMIC_RELAXED,            \
                                       __HIP_MEMORY_SCOPE_AGENT);            \
        }                                                                    \
    } while (0)

    // WAIT: tid0 spins on the group counter, then one block barrier.
    #define HOP_WAIT(TGT) do {                                               \
        if (tid == 0) {                                                      \
            while (__hip_atomic_load(ctr, __ATOMIC_RELAXED,                  \
                                     __HIP_MEMORY_SCOPE_AGENT) < (TGT)) {}   \
        }                                                                    \
        __syncthreads();                                                     \
    } while (0)

    // cell z-part chunk: kc in [K0,K1), accumulated into cc[8]
    #define CCZ(K0, K1) do {                                                 \
        _Pragma("unroll")                                                    \
        for (int ct = 0; ct < 8; ct++) {                                     \
            const uint16_t* bb2_ = wbc + (size_t)(w * 128 + ct * 16 + lm) * 288 + q * 8; \
            _Pragma("unroll")                                                \
            for (int kc = (K0); kc < (K1); kc++) {                           \
                int gz_ = (kc * 4 + q) ^ lm7;                                \
                short8 a_ = *(const short8*)(zcur + lm * 256 + gz_ * 8);     \
                short8 b_ = *(const short8*)(bb2_ + kc * 32);                \
                cc[ct] = __builtin_amdgcn_mfma_f32_16x16x32_bf16(a_, b_, cc[ct], 0, 0, 0); \
            }                                                                \
        }                                                                    \
    } while (0)

    #define MID_COMPUTE(WB, BV) do {                                         \
        floatx4 acc_ = zero;                                                 \
        const uint16_t* bb_ = WB + (size_t)(colbase + cl) * HID + q * 8;     \
        _Pragma("unroll 8")                                                  \
        for (int kc = 0; kc < 32; kc++) {                                    \
            int gh = (kc * 4 + q) ^ lm7;                                     \
            short8 a_ = *(const short8*)(hstg + lm * 1024 + gh * 8);         \
            short8 b_ = *(const short8*)(bb_ + kc * 32);                     \
            acc_ = __builtin_amdgcn_mfma_f32_16x16x32_bf16(a_, b_, acc_, 0, 0, 0); \
        }                                                                    \
        _Pragma("unroll")                                                    \
        for (int i = 0; i < 4; i++)                                          \
            hsl[(q * 4 + i) * 32 + cl] = f2bf(fmaxf(acc_[i] + (BV), 0.f));   \
    } while (0)

    unsigned tgt = 0;
    #pragma unroll 1
    for (int t = 0; t < HOR - TTF; t++) {
        uint16_t* zcur = zst + (t & 1) * (16 * 256);
        uint16_t* znx  = zst + ((t + 1) & 1) * (16 * 256);
        uint16_t* hp = hb + (t & 1) * (4 * 16 * HID);     // step-parity tiles
        uint16_t* h1 = hp;
        uint16_t* h2 = hp + 16 * HID;
        uint16_t* h3 = hp + 2 * 16 * HID;
        uint16_t* h4 = hp + 3 * 16 * HID;

        floatx4 cc[8];
        #pragma unroll
        for (int ct = 0; ct < 8; ct++) cc[ct] = zero;

        // ---- L1 slice from LDS z (local) ----
        {
            floatx4 acc = zero;
            const uint16_t* bb = wb1 + (size_t)(colbase + cl) * LAT + q * 8;
            #pragma unroll
            for (int kc = 0; kc < 8; kc++) {
                int gz = (kc * 4 + q) ^ lm7;
                short8 a = *(const short8*)(zcur + lm * 256 + gz * 8);
                short8 b = *(const short8*)(bb + kc * 32);
                acc = __builtin_amdgcn_mfma_f32_16x16x32_bf16(a, b, acc, 0, 0, 0);
            }
            #pragma unroll
            for (int i = 0; i < 4; i++)
                hsl[(q * 4 + i) * 32 + cl] = f2bf(fmaxf(acc[i] + b1v, 0.f));
        }
        HOP_ARRIVE(h1); tgt += MEMBERS;
        CCZ(0, 2);
        HOP_WAIT(tgt);
        stage_h(h1, hstg, w, L);
        __syncthreads();

        MID_COMPUTE(wb2, b2v);
        HOP_ARRIVE(h2); tgt += MEMBERS;
        CCZ(2, 4);
        HOP_WAIT(tgt);
        stage_h(h2, hstg, w, L);
        __syncthreads();

        MID_COMPUTE(wb3, b3v);
        HOP_ARRIVE(h3); tgt += MEMBERS;
        CCZ(4, 6);
        HOP_WAIT(tgt);
        stage_h(h3, hstg, w, L);
        __syncthreads();

        MID_COMPUTE(wb4, b4v);
        HOP_ARRIVE(h4); tgt += MEMBERS;
        CCZ(6, 8);
        HOP_WAIT(tgt);
        stage_h(h4, hstg, w, L);
        __syncthreads();

        // ---- tail: L5 (redundant), out, cell finish (yh term) ----
        {
            floatx4 a5 = zero;
            const uint16_t* bb = wb5 + (size_t)cl * HID + q * 8;
            #pragma unroll 8
            for (int kc = 0; kc < 32; kc++) {
                int gh = (kc * 4 + q) ^ lm7;
                short8 a = *(const short8*)(hstg + lm * 1024 + gh * 8);
                short8 b = *(const short8*)(bb + kc * 32);
                a5 = __builtin_amdgcn_mfma_f32_16x16x32_bf16(a, b, a5, 0, 0, 0);
            }
            float vout[4];
            #pragma unroll
            for (int i = 0; i < 4; i++) {
                float v = a5[i] + b5v;
                vout[i] = v;
                yscr[(q * 4 + i) * 32 + cl] = f2bf(v);
            }
            if (m == 0) {
                #pragma unroll
                for (int i = 0; i < 4; i++)
                    out[(size_t)(rb + q * 4 + i) * (HOR * OBS) + (TTF + t) * OBS + cl] = vout[i];
            }
        }
        __syncthreads();
        // cell finish: add the yh term (kc=8) to cc[], tanh, write z'
        {
            short8 ay = *(const short8*)(yscr + lm * 32 + q * 8);
            #pragma unroll
            for (int ct = 0; ct < 8; ct++) {
                int ccol = w * 128 + ct * 16 + lm;
                const uint16_t* bb2 = wbc + (size_t)ccol * 288 + q * 8;
                short8 b = *(const short8*)(bb2 + 8 * 32);
                floatx4 v = __builtin_amdgcn_mfma_f32_16x16x32_bf16(ay, b, cc[ct], 0, 0, 0);
                #pragma unroll
                for (int i = 0; i < 4; i++)
                    znx[zswz(q * 4 + i, ccol)] = f2bf(fast_tanh(v[i] + cbv[ct]));
            }
        }
        __syncthreads();
    }
    #undef MID_COMPUTE
    #undef CCZ
    #undef HOP_WAIT
    #undef HOP_ARRIVE
}

// ---------------------------------------------------------------------------
extern "C" void kernel_launch(void* const* d_in, const int* in_sizes, int n_in,
                              void* d_out, int out_size, void* d_ws, size_t ws_size,
                              hipStream_t stream) {
    (void)in_sizes; (void)n_in; (void)out_size; (void)ws_size;
    const float* y    = (const float*)d_in[0];
    const float* W_ih = (const float*)d_in[2];
    const float* W_hh = (const float*)d_in[3];
    const float* b_ih = (const float*)d_in[4];
    const float* b_hh = (const float*)d_in[5];
    const float* W1   = (const float*)d_in[6];
    const float* b1   = (const float*)d_in[7];
    const float* W2   = (const float*)d_in[8];
    const float* b2   = (const float*)d_in[9];
    const float* W3   = (const float*)d_in[10];
    const float* b3   = (const float*)d_in[11];
    const float* W4   = (const float*)d_in[12];
    const float* b4   = (const float*)d_in[13];
    const float* W5   = (const float*)d_in[14];
    const float* b5   = (const float*)d_in[15];
    float* out = (float*)d_out;
    char* ws = (char*)d_ws;

    uint16_t* WB1  = (uint16_t*)(ws + OFF_WB1);
    uint16_t* WB2  = (uint16_t*)(ws + OFF_WB2);
    uint16_t* WB3  = (uint16_t*)(ws + OFF_WB3);
    uint16_t* WB4  = (uint16_t*)(ws + OFF_WB4);
    uint16_t* WB5  = (uint16_t*)(ws + OFF_WB5);
    float*    CB   = (float*)(ws + OFF_CB);
    uint2*    WHH2 = (uint2*)(ws + OFF_WHH2);
    uint2*    WIH2 = (uint2*)(ws + OFF_WIH2);
    float*    ZF   = (float*)(ws + OFF_ZF);
    uint16_t* Zbuf = (uint16_t*)(ws + OFF_Z);
    uint16_t* WBC  = (uint16_t*)(ws + OFF_WBC);
    uint16_t* HB   = (uint16_t*)(ws + OFF_HB);
    unsigned* CTR  = (unsigned*)(ws + OFF_CTR);

    k_cvt<<<(HID*LAT + 255) / 256, 256, 0, stream>>>(W1, WB1, HID * LAT);
    k_cvt<<<(HID*HID + 255) / 256, 256, 0, stream>>>(W2, WB2, HID * HID);
    k_cvt<<<(HID*HID + 255) / 256, 256, 0, stream>>>(W3, WB3, HID * HID);
    k_cvt<<<(HID*HID + 255) / 256, 256, 0, stream>>>(W4, WB4, HID * HID);
    k_cvt<<<(OBS*HID + 255) / 256, 256, 0, stream>>>(W5, WB5, OBS * HID);
    k_cb<<<1, 256, 0, stream>>>(b_ih, b_hh, CB);
    k_pack<<<64, 256, 0, stream>>>(W_hh, WHH2, LAT);
    k_pack<<<8, 256, 0, stream>>>(W_ih, WIH2, OBS);
    k_packc<<<256, 256, 0, stream>>>(W_hh, W_ih, WBC);
    hipMemsetAsync(CTR, 0, GROUPS * 512, stream);

    k_rnn_tf<<<BATCH, 256, 0, stream>>>(y, WHH2, WIH2, CB, Zbuf, ZF);

    // psi: 64-row blocks (halved weight traffic); fall back to the proven
    // 32-row version on any synchronous launch error (e.g. LDS rejection).
    k_psi_bulk64<<<(BATCH * TTF) / 64, 512, 0, stream>>>(
        Zbuf, WB1, WB2, WB3, WB4, WB5, b1, b2, b3, b4, b5, out);
    hipError_t pe = hipGetLastError();
    if (pe != hipSuccess) {
        k_psi_bulk<<<(BATCH * TTF) / 32, 512, 0, stream>>>(
            Zbuf, WB1, WB2, WB3, WB4, WB5, b1, b2, b3, b4, b5, out);
    }

    // Cooperative launch preferred (guaranteed co-residency); on ANY error
    // fall back to a plain launch — 256 blocks at 1+/CU are co-resident.
    void* args[] = {
        (void*)&ZF, (void*)&WB1, (void*)&WB2, (void*)&WB3, (void*)&WB4,
        (void*)&WB5, (void*)&WBC, (void*)&b1, (void*)&b2, (void*)&b3,
        (void*)&b4, (void*)&b5, (void*)&CB, (void*)&HB, (void*)&CTR,
        (void*)&out
    };
    hipError_t ce = hipLaunchCooperativeKernel((const void*)k_ar2,
                                               dim3(ARBLOCKS), dim3(ARTHREADS),
                                               args, 0, stream);
    if (ce != hipSuccess) {
        (void)hipGetLastError();   // clear sticky error
        k_ar2<<<dim3(ARBLOCKS), dim3(ARTHREADS), 0, stream>>>(
            ZF, WB1, WB2, WB3, WB4, WB5, WBC, b1, b2, b3, b4, b5, CB,
            HB, CTR, out);
    }
}